// Round 6
// baseline (495.639 us; speedup 1.0000x reference)
//
#include <hip/hip_runtime.h>
#include <math.h>

#define SEQL 4096
#define L2E 1.44269504088896340736f

#if defined(__has_builtin)
#if __has_builtin(__builtin_amdgcn_exp2f)
#define FAST_EXP2(x) __builtin_amdgcn_exp2f(x)
#endif
#endif
#ifndef FAST_EXP2
#define FAST_EXP2(x) exp2f(x)
#endif

__device__ __forceinline__ float sigmoid_f(float x){ return 1.0f/(1.0f+expf(-x)); }

// ---------------- conv 3x3, pad 1, 64x64 image ----------------
// High-TLP variant: COG=2 -> 1024-2048 blocks (4-8 blocks/CU). Weights staged
// in LDS once (broadcast ds_read, no scalar-cache misses in the loop).
// Inputs via plain global loads (vmcnt), no barriers in the loop.
template<int CI, int CO, int COG, bool RELU, bool RES>
__global__ __launch_bounds__(256,4) void conv3x3_k(const float* __restrict__ in,
    const float* __restrict__ wgt, const float* __restrict__ bias,
    const float* __restrict__ res, float* __restrict__ out)
{
  __shared__ float lw[COG*CI*9];
  const int tid  = threadIdx.x;
  const int lane = tid & 63;                    // w
  const int ty   = tid >> 6;                    // 0..3 (wave id)
  const int h    = blockIdx.x*4 + ty;           // output row (wave-uniform)
  const int co0  = blockIdx.y*COG;
  const int b    = blockIdx.z;
  // stage weights for this co-group (contiguous in wgt): COG*CI*9 floats
  for (int i=tid; i<COG*CI*9; i+=256) lw[i] = wgt[(size_t)co0*CI*9 + i];
  __syncthreads();

  const int wl = (lane==0)  ? 0  : lane-1;      // clamped (stay in-bounds)
  const int wr = (lane==63) ? 63 : lane+1;
  float acc[COG];
  #pragma unroll
  for (int u=0;u<COG;++u) acc[u] = bias[co0+u];

  #pragma unroll 4
  for (int ci=0; ci<CI; ++ci){
    const float* p = in + ((size_t)(b*CI+ci))*4096;
    float L[3], M[3], R[3];
    #pragma unroll
    for (int j=0;j<3;++j){
      int hh = h - 1 + j;                       // wave-uniform bounds branch
      if (hh>=0 && hh<64){
        const float* row = p + hh*64;
        float lv = row[wl], mv = row[lane], rv = row[wr];
        if (lane==0)  lv = 0.0f;
        if (lane==63) rv = 0.0f;
        L[j]=lv; M[j]=mv; R[j]=rv;
      } else { L[j]=0.0f; M[j]=0.0f; R[j]=0.0f; }
    }
    #pragma unroll
    for (int u=0;u<COG;++u){
      const float* wp = lw + (u*CI + ci)*9;     // wave-uniform -> LDS broadcast
      #pragma unroll
      for (int j=0;j<3;++j){
        acc[u] = fmaf(L[j], wp[j*3+0], acc[u]);
        acc[u] = fmaf(M[j], wp[j*3+1], acc[u]);
        acc[u] = fmaf(R[j], wp[j*3+2], acc[u]);
      }
    }
  }
  #pragma unroll
  for (int u=0;u<COG;++u){
    size_t ob = ((size_t)(b*CO+co0+u))*4096 + (size_t)h*64 + lane;
    float v = acc[u];
    if constexpr (RES)  v += res[ob];
    if constexpr (RELU) v = fmaxf(v, 0.0f);
    out[ob] = v;
  }
}

// ---------------- LayerNorm(32) + in_proj (32->128) + silu on z half --------
__global__ __launch_bounds__(512) void ln_inproj_k(const float* __restrict__ x2,
    const float* __restrict__ g, const float* __restrict__ be,
    const float* __restrict__ Wip, float* __restrict__ xm_pre, float* __restrict__ sz)
{
  __shared__ float xn[64][36];
  const int tid = threadIdx.x, lane = tid & 63, ty = tid >> 6;
  const int bi = blockIdx.x >> 6;
  const int l0 = (blockIdx.x & 63) << 6;
  if (ty == 0){
    const float* row = x2 + (size_t)bi*131072 + (size_t)(l0+lane)*32;
    float v[32];
    #pragma unroll
    for (int c=0;c<32;c+=4){
      float4 f = *(const float4*)(row + c);
      v[c]=f.x; v[c+1]=f.y; v[c+2]=f.z; v[c+3]=f.w;
    }
    float p[8];
    #pragma unroll
    for (int j2=0;j2<8;++j2) p[j2]=v[j2];
    #pragma unroll
    for (int i=8;i<32;i+=8){
      #pragma unroll
      for (int j2=0;j2<8;++j2) p[j2]+=v[i+j2];
    }
    float mu = (((p[0]+p[1])+(p[2]+p[3]))+((p[4]+p[5])+(p[6]+p[7]))) * 0.03125f;
    float q[8];
    #pragma unroll
    for (int j2=0;j2<8;++j2){ float dd=v[j2]-mu; q[j2]=dd*dd; }
    #pragma unroll
    for (int i=8;i<32;i+=8){
      #pragma unroll
      for (int j2=0;j2<8;++j2){ float dd=v[i+j2]-mu; q[j2]+=dd*dd; }
    }
    float var = (((q[0]+q[1])+(q[2]+q[3]))+((q[4]+q[5])+(q[6]+q[7]))) * 0.03125f;
    float rstd = 1.0f / sqrtf(var + 1e-5f);
    #pragma unroll
    for (int c=0;c<32;++c) xn[lane][c] = (v[c]-mu)*rstd*g[c] + be[c];
  }
  __syncthreads();
  float xv[32];
  #pragma unroll
  for (int c=0;c<32;c+=4){
    float4 f = *(const float4*)(&xn[lane][c]);
    xv[c]=f.x; xv[c+1]=f.y; xv[c+2]=f.z; xv[c+3]=f.w;
  }
  #pragma unroll
  for (int jj=0;jj<16;++jj){
    int j = (ty<<4) + jj;
    const float* wr = Wip + j*32;
    float acc = 0.0f;
    #pragma unroll
    for (int c=0;c<32;++c) acc = fmaf(xv[c], wr[c], acc);
    size_t o = ((size_t)(bi*64 + (j & 63)))*SEQL + l0 + lane;
    if (j < 64) xm_pre[o] = acc;
    else        sz[o] = acc * sigmoid_f(acc);
  }
}

// ---- fused: depthwise causal conv1d+silu, x_proj (64->66), dt_proj+softplus, B/C split
__global__ __launch_bounds__(512) void xproj_k(const float* __restrict__ xm_pre,
    const float* __restrict__ cw, const float* __restrict__ cb,
    const float* __restrict__ Wxp, const float* __restrict__ Wdt,
    const float* __restrict__ bdt, float* __restrict__ xm2,
    float* __restrict__ delta, float* __restrict__ Bm, float* __restrict__ Cm)
{
  __shared__ float xs[64][68];   // xs[d][c] = xm_pre[l0-3+c], c in 0..66
  __shared__ float xt[64][68];   // xt[l][d] = silu(conv) transposed
  __shared__ float xd[64][68];   // xd[l][j], j in 0..65
  const int tid = threadIdx.x, lane = tid & 63, ty = tid >> 6;
  const int bi = blockIdx.x >> 6;
  const int l0 = (blockIdx.x & 63) << 6;
  for (int r=ty; r<64; r+=8){
    const float* src = xm_pre + ((size_t)(bi*64+r))*SEQL + l0;
    float v = 0.0f;
    if (l0 + lane - 3 >= 0) v = src[lane-3];
    xs[r][lane] = v;
    if (lane < 3) xs[r][64+lane] = src[61+lane];
  }
  __syncthreads();
  for (int r=ty; r<64; r+=8){
    float w0=cw[r*4], w1=cw[r*4+1], w2=cw[r*4+2], w3=cw[r*4+3], bv=cb[r];
    float a = xs[r][lane]*w0 + xs[r][lane+1]*w1 + xs[r][lane+2]*w2 + xs[r][lane+3]*w3 + bv;
    float s = a * sigmoid_f(a);
    xt[lane][r] = s;
    xm2[((size_t)(bi*64+r))*SEQL + l0 + lane] = s;
  }
  __syncthreads();
  float xv[64];
  #pragma unroll
  for (int c=0;c<64;c+=4){
    float4 f = *(const float4*)(&xt[lane][c]);
    xv[c]=f.x; xv[c+1]=f.y; xv[c+2]=f.z; xv[c+3]=f.w;
  }
  for (int j=ty; j<66; j+=8){
    const float* wr = Wxp + j*64;
    float acc = 0.0f;
    #pragma unroll
    for (int c=0;c<64;++c) acc = fmaf(xv[c], wr[c], acc);
    xd[lane][j] = acc;
  }
  __syncthreads();
  float dt0 = xd[lane][0], dt1 = xd[lane][1];
  #pragma unroll
  for (int k=0;k<8;++k){
    int d2 = ty*8 + k;
    float v = dt0*Wdt[d2*2] + dt1*Wdt[d2*2+1] + bdt[d2];
    float sp = fmaxf(v,0.0f) + log1pf(expf(-fabsf(v)));
    delta[((size_t)(bi*64+d2))*SEQL + l0 + lane] = sp;
  }
  const int which = ty >> 2, gq = ty & 3;
  float* dst = which ? Cm : Bm;
  size_t base = ((size_t)bi*SEQL + l0 + lane)*32 + gq*8;
  const int s0 = 2 + which*32 + gq*8;
  float4 f0, f1;
  f0.x = xd[lane][s0+0]; f0.y = xd[lane][s0+1]; f0.z = xd[lane][s0+2]; f0.w = xd[lane][s0+3];
  f1.x = xd[lane][s0+4]; f1.y = xd[lane][s0+5]; f1.z = xd[lane][s0+6]; f1.w = xd[lane][s0+7];
  *(float4*)(dst + base)     = f0;
  *(float4*)(dst + base + 4) = f1;
}

// ---------------- selective scan: 3-kernel chunked scan, chunk=64 ----------
__global__ __launch_bounds__(256) void scan_p1(const float* __restrict__ dlt,
    const float* __restrict__ xssm, const float* __restrict__ Bm,
    const float* __restrict__ A_log, float* __restrict__ cA, float* __restrict__ cH)
{
  const int tid = threadIdx.x;
  const int n = tid & 31;
  const int chunk = (blockIdx.x & 7)*8 + (tid >> 5);
  const int bd = blockIdx.x >> 3;
  const int b = bd >> 6, d = bd & 63;
  const int l0 = chunk << 6;
  const float Av2 = -expf(A_log[d*32+n]) * L2E;
  const float* del = dlt  + (size_t)bd*SEQL + l0;
  const float* xp  = xssm + (size_t)bd*SEQL + l0;
  const float* Bp  = Bm + ((size_t)b*SEQL + l0)*32 + n;
  float h = 0.0f, aP = 1.0f;
  #pragma unroll 4
  for (int i0=0;i0<64;i0+=4){
    float4 d4 = *(const float4*)(del+i0);
    float4 x4 = *(const float4*)(xp +i0);
    float b0 = Bp[(i0+0)*32], b1 = Bp[(i0+1)*32], b2 = Bp[(i0+2)*32], b3 = Bp[(i0+3)*32];
    float a0 = FAST_EXP2(d4.x*Av2); h = fmaf(a0,h, d4.x*b0*x4.x); aP *= a0;
    float a1 = FAST_EXP2(d4.y*Av2); h = fmaf(a1,h, d4.y*b1*x4.y); aP *= a1;
    float a2 = FAST_EXP2(d4.z*Av2); h = fmaf(a2,h, d4.z*b2*x4.z); aP *= a2;
    float a3 = FAST_EXP2(d4.w*Av2); h = fmaf(a3,h, d4.w*b3*x4.w); aP *= a3;
  }
  int idx = (bd*64+chunk)*32 + n;
  cA[idx] = aP; cH[idx] = h;
}

__global__ __launch_bounds__(128) void scan_comb(const float* __restrict__ cA,
    float* __restrict__ cH)
{
  const int gid = blockIdx.x*128 + threadIdx.x;   // 8192 = 256 bd x 32 n
  const int n = gid & 31, bd = gid >> 5;
  const size_t base = (size_t)bd*64*32 + n;
  float hrun = 0.0f;
  #pragma unroll 8
  for (int c=0;c<64;++c){
    float ac = cA[base + c*32];
    float hc = cH[base + c*32];
    cH[base + c*32] = hrun;                        // exclusive prefix
    hrun = fmaf(ac, hrun, hc);
  }
}

__global__ __launch_bounds__(256) void scan_p2(const float* __restrict__ dlt,
    const float* __restrict__ xssm, const float* __restrict__ Bm,
    const float* __restrict__ Cm, const float* __restrict__ A_log,
    const float* __restrict__ Dp, const float* __restrict__ sz,
    const float* __restrict__ cH, float* __restrict__ yt)
{
  const int tid = threadIdx.x;
  const int n = tid & 31;
  const int chunk = (blockIdx.x & 7)*8 + (tid >> 5);
  const int bd = blockIdx.x >> 3;
  const int b = bd >> 6, d = bd & 63;
  const int l0 = chunk << 6;
  const float Av2 = -expf(A_log[d*32+n]) * L2E;
  const float Dv = Dp[d];
  const float* del = dlt  + (size_t)bd*SEQL + l0;
  const float* xp  = xssm + (size_t)bd*SEQL + l0;
  const float* szp = sz   + (size_t)bd*SEQL + l0;
  const float* Bp  = Bm + ((size_t)b*SEQL + l0)*32 + n;
  const float* Cp  = Cm + ((size_t)b*SEQL + l0)*32 + n;
  float* yp = yt + (size_t)bd*SEQL + l0;
  float h = cH[(bd*64+chunk)*32 + n];
  #pragma unroll 2
  for (int i0=0;i0<64;i0+=4){
    float4 d4 = *(const float4*)(del+i0);
    float4 x4 = *(const float4*)(xp +i0);
    float4 s4 = *(const float4*)(szp+i0);
    float b0 = Bp[(i0+0)*32], b1 = Bp[(i0+1)*32], b2 = Bp[(i0+2)*32], b3 = Bp[(i0+3)*32];
    float c0 = Cp[(i0+0)*32], c1 = Cp[(i0+1)*32], c2 = Cp[(i0+2)*32], c3 = Cp[(i0+3)*32];
    float a0 = FAST_EXP2(d4.x*Av2); h = fmaf(a0,h, d4.x*b0*x4.x);
    float v0 = h*c0;
    float a1 = FAST_EXP2(d4.y*Av2); h = fmaf(a1,h, d4.y*b1*x4.y);
    float v1 = h*c1;
    float a2 = FAST_EXP2(d4.z*Av2); h = fmaf(a2,h, d4.z*b2*x4.z);
    float v2 = h*c2;
    float a3 = FAST_EXP2(d4.w*Av2); h = fmaf(a3,h, d4.w*b3*x4.w);
    float v3 = h*c3;
    v0 += __shfl_xor(v0,16); v0 += __shfl_xor(v0,8); v0 += __shfl_xor(v0,4);
    v0 += __shfl_xor(v0,2);  v0 += __shfl_xor(v0,1);
    v1 += __shfl_xor(v1,16); v1 += __shfl_xor(v1,8); v1 += __shfl_xor(v1,4);
    v1 += __shfl_xor(v1,2);  v1 += __shfl_xor(v1,1);
    v2 += __shfl_xor(v2,16); v2 += __shfl_xor(v2,8); v2 += __shfl_xor(v2,4);
    v2 += __shfl_xor(v2,2);  v2 += __shfl_xor(v2,1);
    v3 += __shfl_xor(v3,16); v3 += __shfl_xor(v3,8); v3 += __shfl_xor(v3,4);
    v3 += __shfl_xor(v3,2);  v3 += __shfl_xor(v3,1);
    if (n==0){
      yp[i0+0] = fmaf(x4.x, Dv, v0) * s4.x;
      yp[i0+1] = fmaf(x4.y, Dv, v1) * s4.y;
      yp[i0+2] = fmaf(x4.z, Dv, v2) * s4.z;
      yp[i0+3] = fmaf(x4.w, Dv, v3) * s4.w;
    }
  }
}

// ---------------- out_proj (64->32) into (b,c,l) = NCHW image --------------
__global__ __launch_bounds__(512) void outproj_k(const float* __restrict__ yt,
    const float* __restrict__ Wout, float* __restrict__ ym)
{
  __shared__ float ys[64][68];    // ys[l][d]
  const int tid = threadIdx.x, lane = tid & 63, ty = tid >> 6;
  const int bi = blockIdx.x >> 6;
  const int l0 = (blockIdx.x & 63) << 6;
  for (int r=ty; r<64; r+=8)
    ys[lane][r] = yt[((size_t)(bi*64+r))*SEQL + l0 + lane];
  __syncthreads();
  float yv[64];
  #pragma unroll
  for (int c=0;c<64;c+=4){
    float4 f = *(const float4*)(&ys[lane][c]);
    yv[c]=f.x; yv[c+1]=f.y; yv[c+2]=f.z; yv[c+3]=f.w;
  }
  #pragma unroll
  for (int jj=0;jj<4;++jj){
    int j = ty*4 + jj;
    const float* wr = Wout + j*64;
    float acc = 0.0f;
    #pragma unroll
    for (int c=0;c<64;++c) acc = fmaf(yv[c], wr[c], acc);
    ym[((size_t)(bi*32+j))*SEQL + l0 + lane] = acc;
  }
}

extern "C" void kernel_launch(void* const* d_in, const int* in_sizes, int n_in,
                              void* d_out, int out_size, void* d_ws, size_t ws_size,
                              hipStream_t stream) {
  const float* x        = (const float*)d_in[0];
  const float* conv1_w  = (const float*)d_in[1];
  const float* conv1_b  = (const float*)d_in[2];
  const float* conv2_w  = (const float*)d_in[3];
  const float* conv2_b  = (const float*)d_in[4];
  const float* ln_g     = (const float*)d_in[5];
  const float* ln_b     = (const float*)d_in[6];
  const float* in_proj_w= (const float*)d_in[7];
  const float* conv1d_w = (const float*)d_in[8];
  const float* conv1d_b = (const float*)d_in[9];
  const float* x_proj_w = (const float*)d_in[10];
  const float* dt_proj_w= (const float*)d_in[11];
  const float* dt_proj_b= (const float*)d_in[12];
  const float* A_log    = (const float*)d_in[13];
  const float* Dp       = (const float*)d_in[14];
  const float* out_proj_w=(const float*)d_in[15];
  const float* smooth_w = (const float*)d_in[16];
  const float* smooth_b = (const float*)d_in[17];
  float* out = (float*)d_out;

  float* ws = (float*)d_ws;
  float* t      = ws;                 // (4,64,64,64)  1048576  (free after conv2)
  float* x2     = t      + 1048576;   // (4,32,4096)    524288
  float* xm_pre = x2     + 524288;    // (4,64,4096)   1048576
  float* xm2    = xm_pre + 1048576;   // (4,64,4096)   1048576
  float* szb    = xm2    + 1048576;   // (4,64,4096)   1048576
  float* dlt    = szb    + 1048576;   // (4,64,4096)   1048576
  float* Bmat   = dlt    + 1048576;   // (4,4096,32)    524288
  float* Cmat   = Bmat   + 524288;    // (4,4096,32)    524288
  float* yt     = Cmat   + 524288;    // (4,64,4096)   1048576
  float* ym     = yt     + 1048576;   // (4,32,4096)    524288
  float* cA     = t;                  // (256,64,32)    524288 (aliases t)
  float* cH     = t + 524288;         // (256,64,32)    524288 (aliases t)

  // conv1: 32->64, COG=2 -> grid (16,32,4)=2048 blocks (8 blocks/CU)
  conv3x3_k<32,64,2,true ,false><<<dim3(16,32,4), 256, 0, stream>>>(x,  conv1_w, conv1_b, nullptr, t);
  // conv2: 64->32 + residual, COG=2 -> grid (16,16,4)=1024 blocks (4 blocks/CU)
  conv3x3_k<64,32,2,false,true ><<<dim3(16,16,4), 256, 0, stream>>>(t,  conv2_w, conv2_b, x,       x2);
  ln_inproj_k <<<256, 512, 0, stream>>>(x2, ln_g, ln_b, in_proj_w, xm_pre, szb);
  xproj_k     <<<256, 512, 0, stream>>>(xm_pre, conv1d_w, conv1d_b, x_proj_w, dt_proj_w, dt_proj_b,
                                        xm2, dlt, Bmat, Cmat);
  scan_p1     <<<2048, 256, 0, stream>>>(dlt, xm2, Bmat, A_log, cA, cH);
  scan_comb   <<<64,   128, 0, stream>>>(cA, cH);
  scan_p2     <<<2048, 256, 0, stream>>>(dlt, xm2, Bmat, Cmat, A_log, Dp, szb, cH, yt);
  outproj_k   <<<256, 512, 0, stream>>>(yt, out_proj_w, ym);
  // smooth: 32->32, COG=2 -> grid (16,16,4)=1024 blocks
  conv3x3_k<32,32,2,false,false><<<dim3(16,16,4), 256, 0, stream>>>(ym, smooth_w, smooth_b, nullptr, out);
}

// Round 7
// 368.878 us; speedup vs baseline: 1.3436x; 1.3436x over previous
//
#include <hip/hip_runtime.h>
#include <math.h>

#define SEQL 4096
#define L2E 1.44269504088896340736f

#if defined(__has_builtin)
#if __has_builtin(__builtin_amdgcn_exp2f)
#define FAST_EXP2(x) __builtin_amdgcn_exp2f(x)
#endif
#endif
#ifndef FAST_EXP2
#define FAST_EXP2(x) exp2f(x)
#endif

__device__ __forceinline__ float sigmoid_f(float x){ return 1.0f/(1.0f+expf(-x)); }

// ---- conv3x3 inner accumulation over a ci-slice (branch-free when !EDGE) ----
template<int CIT, int COG, bool EDGE>
__device__ __forceinline__ void conv_accum(const float* __restrict__ pc, // input base: (b,ci0) channel, +h*64 row
    const float* __restrict__ wp0,   // weights base: ((co0)*CI + ci0)*9 ; stride CI*9 per cout
    int CI9, int h, int lane, int wl, int wr, float* acc)
{
  #pragma unroll 2
  for (int ci=0; ci<CIT; ++ci){
    const float* base = pc + (size_t)ci*4096 + h*64;
    float v[3][3];
    #pragma unroll
    for (int j=0;j<3;++j){
      float lv, mv, rv;
      if constexpr (EDGE){
        int hh = h - 1 + j;
        bool ok = (hh>=0) && (hh<64);
        const float* r = base + (ok ? (j-1)*64 : 0);
        lv = r[wl]; mv = r[lane]; rv = r[wr];
        if (!ok){ lv=0.0f; mv=0.0f; rv=0.0f; }
      } else {
        const float* r = base + (j-1)*64;
        lv = r[wl]; mv = r[lane]; rv = r[wr];
      }
      if (lane==0)  lv = 0.0f;
      if (lane==63) rv = 0.0f;
      v[j][0]=lv; v[j][1]=mv; v[j][2]=rv;
    }
    #pragma unroll
    for (int u=0;u<COG;++u){
      const float* wp = wp0 + u*CI9 + ci*9;     // wave-uniform -> s_load
      #pragma unroll
      for (int j=0;j<3;++j){
        acc[u] = fmaf(v[j][0], wp[j*3+0], acc[u]);
        acc[u] = fmaf(v[j][1], wp[j*3+1], acc[u]);
        acc[u] = fmaf(v[j][2], wp[j*3+2], acc[u]);
      }
    }
  }
}

// ---------------- conv 3x3, pad 1, 64x64 image, ksplit=4 ----------------
// Block = 256 thr: lane=w, ty = ci-slice (CI/4 channels each). One output row
// per block, COG couts. Grid 64*CO/COG*4 = 2048 blocks (8 blocks/CU).
// Cross-wave LDS reduction at the end. No spill: launch_bounds(256,6).
template<int CI, int CO, int COG, bool RELU, bool RES>
__global__ __launch_bounds__(256,6) void conv3x3_k(const float* __restrict__ in,
    const float* __restrict__ wgt, const float* __restrict__ bias,
    const float* __restrict__ res, float* __restrict__ out)
{
  constexpr int CIT = CI/4;
  __shared__ float red[4][COG][66];
  const int lane = threadIdx.x & 63;            // w
  const int ty   = threadIdx.x >> 6;            // ci-slice index 0..3
  const int h    = blockIdx.x;                  // output row
  const int co0  = blockIdx.y*COG;
  const int b    = blockIdx.z;
  const int wl = (lane==0)  ? 0  : lane-1;
  const int wr = (lane==63) ? 63 : lane+1;
  float acc[COG];
  #pragma unroll
  for (int u=0;u<COG;++u) acc[u] = 0.0f;

  const float* pc  = in + ((size_t)(b*CI) + ty*CIT)*4096;
  const float* wp0 = wgt + ((size_t)co0*CI + ty*CIT)*9;
  if (h>0 && h<63)
    conv_accum<CIT,COG,false>(pc, wp0, CI*9, h, lane, wl, wr, acc);
  else
    conv_accum<CIT,COG,true >(pc, wp0, CI*9, h, lane, wl, wr, acc);

  #pragma unroll
  for (int u=0;u<COG;++u) red[ty][u][lane] = acc[u];
  __syncthreads();
  constexpr int CPT = COG/4;                    // couts per reducing wave
  #pragma unroll
  for (int k=0;k<CPT;++k){
    int u = ty*CPT + k;
    float s = ((red[0][u][lane]+red[1][u][lane])+(red[2][u][lane]+red[3][u][lane]))
              + bias[co0+u];
    size_t ob = ((size_t)(b*CO+co0+u))*4096 + (size_t)h*64 + lane;
    if constexpr (RES)  s += res[ob];
    if constexpr (RELU) s = fmaxf(s, 0.0f);
    out[ob] = s;
  }
}

// ---------------- LayerNorm(32) + in_proj (32->128) + silu on z half --------
__global__ __launch_bounds__(512) void ln_inproj_k(const float* __restrict__ x2,
    const float* __restrict__ g, const float* __restrict__ be,
    const float* __restrict__ Wip, float* __restrict__ xm_pre, float* __restrict__ sz)
{
  __shared__ float xn[64][36];
  const int tid = threadIdx.x, lane = tid & 63, ty = tid >> 6;
  const int bi = blockIdx.x >> 6;
  const int l0 = (blockIdx.x & 63) << 6;
  if (ty == 0){
    const float* row = x2 + (size_t)bi*131072 + (size_t)(l0+lane)*32;
    float v[32];
    #pragma unroll
    for (int c=0;c<32;c+=4){
      float4 f = *(const float4*)(row + c);
      v[c]=f.x; v[c+1]=f.y; v[c+2]=f.z; v[c+3]=f.w;
    }
    float p[8];
    #pragma unroll
    for (int j2=0;j2<8;++j2) p[j2]=v[j2];
    #pragma unroll
    for (int i=8;i<32;i+=8){
      #pragma unroll
      for (int j2=0;j2<8;++j2) p[j2]+=v[i+j2];
    }
    float mu = (((p[0]+p[1])+(p[2]+p[3]))+((p[4]+p[5])+(p[6]+p[7]))) * 0.03125f;
    float q[8];
    #pragma unroll
    for (int j2=0;j2<8;++j2){ float dd=v[j2]-mu; q[j2]=dd*dd; }
    #pragma unroll
    for (int i=8;i<32;i+=8){
      #pragma unroll
      for (int j2=0;j2<8;++j2){ float dd=v[i+j2]-mu; q[j2]+=dd*dd; }
    }
    float var = (((q[0]+q[1])+(q[2]+q[3]))+((q[4]+q[5])+(q[6]+q[7]))) * 0.03125f;
    float rstd = 1.0f / sqrtf(var + 1e-5f);
    #pragma unroll
    for (int c=0;c<32;++c) xn[lane][c] = (v[c]-mu)*rstd*g[c] + be[c];
  }
  __syncthreads();
  float xv[32];
  #pragma unroll
  for (int c=0;c<32;c+=4){
    float4 f = *(const float4*)(&xn[lane][c]);
    xv[c]=f.x; xv[c+1]=f.y; xv[c+2]=f.z; xv[c+3]=f.w;
  }
  #pragma unroll
  for (int jj=0;jj<16;++jj){
    int j = (ty<<4) + jj;
    const float* wr = Wip + j*32;
    float acc = 0.0f;
    #pragma unroll
    for (int c=0;c<32;++c) acc = fmaf(xv[c], wr[c], acc);
    size_t o = ((size_t)(bi*64 + (j & 63)))*SEQL + l0 + lane;
    if (j < 64) xm_pre[o] = acc;
    else        sz[o] = acc * sigmoid_f(acc);
  }
}

// ---- fused: depthwise causal conv1d+silu, x_proj (64->66), dt_proj+softplus, B/C split
__global__ __launch_bounds__(512) void xproj_k(const float* __restrict__ xm_pre,
    const float* __restrict__ cw, const float* __restrict__ cb,
    const float* __restrict__ Wxp, const float* __restrict__ Wdt,
    const float* __restrict__ bdt, float* __restrict__ xm2,
    float* __restrict__ delta, float* __restrict__ Bm, float* __restrict__ Cm)
{
  __shared__ float xs[64][68];   // xs[d][c] = xm_pre[l0-3+c], c in 0..66
  __shared__ float xt[64][68];   // xt[l][d] = silu(conv) transposed
  __shared__ float xd[64][68];   // xd[l][j], j in 0..65
  const int tid = threadIdx.x, lane = tid & 63, ty = tid >> 6;
  const int bi = blockIdx.x >> 6;
  const int l0 = (blockIdx.x & 63) << 6;
  for (int r=ty; r<64; r+=8){
    const float* src = xm_pre + ((size_t)(bi*64+r))*SEQL + l0;
    float v = 0.0f;
    if (l0 + lane - 3 >= 0) v = src[lane-3];
    xs[r][lane] = v;
    if (lane < 3) xs[r][64+lane] = src[61+lane];
  }
  __syncthreads();
  for (int r=ty; r<64; r+=8){
    float w0=cw[r*4], w1=cw[r*4+1], w2=cw[r*4+2], w3=cw[r*4+3], bv=cb[r];
    float a = xs[r][lane]*w0 + xs[r][lane+1]*w1 + xs[r][lane+2]*w2 + xs[r][lane+3]*w3 + bv;
    float s = a * sigmoid_f(a);
    xt[lane][r] = s;
    xm2[((size_t)(bi*64+r))*SEQL + l0 + lane] = s;
  }
  __syncthreads();
  float xv[64];
  #pragma unroll
  for (int c=0;c<64;c+=4){
    float4 f = *(const float4*)(&xt[lane][c]);
    xv[c]=f.x; xv[c+1]=f.y; xv[c+2]=f.z; xv[c+3]=f.w;
  }
  for (int j=ty; j<66; j+=8){
    const float* wr = Wxp + j*64;
    float acc = 0.0f;
    #pragma unroll
    for (int c=0;c<64;++c) acc = fmaf(xv[c], wr[c], acc);
    xd[lane][j] = acc;
  }
  __syncthreads();
  float dt0 = xd[lane][0], dt1 = xd[lane][1];
  #pragma unroll
  for (int k=0;k<8;++k){
    int d2 = ty*8 + k;
    float v = dt0*Wdt[d2*2] + dt1*Wdt[d2*2+1] + bdt[d2];
    float sp = fmaxf(v,0.0f) + log1pf(expf(-fabsf(v)));
    delta[((size_t)(bi*64+d2))*SEQL + l0 + lane] = sp;
  }
  const int which = ty >> 2, gq = ty & 3;
  float* dst = which ? Cm : Bm;
  size_t base = ((size_t)bi*SEQL + l0 + lane)*32 + gq*8;
  const int s0 = 2 + which*32 + gq*8;
  float4 f0, f1;
  f0.x = xd[lane][s0+0]; f0.y = xd[lane][s0+1]; f0.z = xd[lane][s0+2]; f0.w = xd[lane][s0+3];
  f1.x = xd[lane][s0+4]; f1.y = xd[lane][s0+5]; f1.z = xd[lane][s0+6]; f1.w = xd[lane][s0+7];
  *(float4*)(dst + base)     = f0;
  *(float4*)(dst + base + 4) = f1;
}

// ---------------- selective scan: 3-kernel chunked scan, chunk=64 ----------
__global__ __launch_bounds__(256) void scan_p1(const float* __restrict__ dlt,
    const float* __restrict__ xssm, const float* __restrict__ Bm,
    const float* __restrict__ A_log, float* __restrict__ cA, float* __restrict__ cH)
{
  const int tid = threadIdx.x;
  const int n = tid & 31;
  const int chunk = (blockIdx.x & 7)*8 + (tid >> 5);
  const int bd = blockIdx.x >> 3;
  const int b = bd >> 6, d = bd & 63;
  const int l0 = chunk << 6;
  const float Av2 = -expf(A_log[d*32+n]) * L2E;
  const float* del = dlt  + (size_t)bd*SEQL + l0;
  const float* xp  = xssm + (size_t)bd*SEQL + l0;
  const float* Bp  = Bm + ((size_t)b*SEQL + l0)*32 + n;
  float h = 0.0f, aP = 1.0f;
  #pragma unroll 4
  for (int i0=0;i0<64;i0+=4){
    float4 d4 = *(const float4*)(del+i0);
    float4 x4 = *(const float4*)(xp +i0);
    float b0 = Bp[(i0+0)*32], b1 = Bp[(i0+1)*32], b2 = Bp[(i0+2)*32], b3 = Bp[(i0+3)*32];
    float a0 = FAST_EXP2(d4.x*Av2); h = fmaf(a0,h, d4.x*b0*x4.x); aP *= a0;
    float a1 = FAST_EXP2(d4.y*Av2); h = fmaf(a1,h, d4.y*b1*x4.y); aP *= a1;
    float a2 = FAST_EXP2(d4.z*Av2); h = fmaf(a2,h, d4.z*b2*x4.z); aP *= a2;
    float a3 = FAST_EXP2(d4.w*Av2); h = fmaf(a3,h, d4.w*b3*x4.w); aP *= a3;
  }
  int idx = (bd*64+chunk)*32 + n;
  cA[idx] = aP; cH[idx] = h;
}

__global__ __launch_bounds__(128) void scan_comb(const float* __restrict__ cA,
    float* __restrict__ cH)
{
  const int gid = blockIdx.x*128 + threadIdx.x;   // 8192 = 256 bd x 32 n
  const int n = gid & 31, bd = gid >> 5;
  const size_t base = (size_t)bd*64*32 + n;
  float hrun = 0.0f;
  #pragma unroll 8
  for (int c=0;c<64;++c){
    float ac = cA[base + c*32];
    float hc = cH[base + c*32];
    cH[base + c*32] = hrun;                        // exclusive prefix
    hrun = fmaf(ac, hrun, hc);
  }
}

__global__ __launch_bounds__(256) void scan_p2(const float* __restrict__ dlt,
    const float* __restrict__ xssm, const float* __restrict__ Bm,
    const float* __restrict__ Cm, const float* __restrict__ A_log,
    const float* __restrict__ Dp, const float* __restrict__ sz,
    const float* __restrict__ cH, float* __restrict__ yt)
{
  const int tid = threadIdx.x;
  const int n = tid & 31;
  const int chunk = (blockIdx.x & 7)*8 + (tid >> 5);
  const int bd = blockIdx.x >> 3;
  const int b = bd >> 6, d = bd & 63;
  const int l0 = chunk << 6;
  const float Av2 = -expf(A_log[d*32+n]) * L2E;
  const float Dv = Dp[d];
  const float* del = dlt  + (size_t)bd*SEQL + l0;
  const float* xp  = xssm + (size_t)bd*SEQL + l0;
  const float* szp = sz   + (size_t)bd*SEQL + l0;
  const float* Bp  = Bm + ((size_t)b*SEQL + l0)*32 + n;
  const float* Cp  = Cm + ((size_t)b*SEQL + l0)*32 + n;
  float* yp = yt + (size_t)bd*SEQL + l0;
  float h = cH[(bd*64+chunk)*32 + n];
  #pragma unroll 2
  for (int i0=0;i0<64;i0+=4){
    float4 d4 = *(const float4*)(del+i0);
    float4 x4 = *(const float4*)(xp +i0);
    float4 s4 = *(const float4*)(szp+i0);
    float b0 = Bp[(i0+0)*32], b1 = Bp[(i0+1)*32], b2 = Bp[(i0+2)*32], b3 = Bp[(i0+3)*32];
    float c0 = Cp[(i0+0)*32], c1 = Cp[(i0+1)*32], c2 = Cp[(i0+2)*32], c3 = Cp[(i0+3)*32];
    float a0 = FAST_EXP2(d4.x*Av2); h = fmaf(a0,h, d4.x*b0*x4.x);
    float v0 = h*c0;
    float a1 = FAST_EXP2(d4.y*Av2); h = fmaf(a1,h, d4.y*b1*x4.y);
    float v1 = h*c1;
    float a2 = FAST_EXP2(d4.z*Av2); h = fmaf(a2,h, d4.z*b2*x4.z);
    float v2 = h*c2;
    float a3 = FAST_EXP2(d4.w*Av2); h = fmaf(a3,h, d4.w*b3*x4.w);
    float v3 = h*c3;
    v0 += __shfl_xor(v0,16); v0 += __shfl_xor(v0,8); v0 += __shfl_xor(v0,4);
    v0 += __shfl_xor(v0,2);  v0 += __shfl_xor(v0,1);
    v1 += __shfl_xor(v1,16); v1 += __shfl_xor(v1,8); v1 += __shfl_xor(v1,4);
    v1 += __shfl_xor(v1,2);  v1 += __shfl_xor(v1,1);
    v2 += __shfl_xor(v2,16); v2 += __shfl_xor(v2,8); v2 += __shfl_xor(v2,4);
    v2 += __shfl_xor(v2,2);  v2 += __shfl_xor(v2,1);
    v3 += __shfl_xor(v3,16); v3 += __shfl_xor(v3,8); v3 += __shfl_xor(v3,4);
    v3 += __shfl_xor(v3,2);  v3 += __shfl_xor(v3,1);
    if (n==0){
      yp[i0+0] = fmaf(x4.x, Dv, v0) * s4.x;
      yp[i0+1] = fmaf(x4.y, Dv, v1) * s4.y;
      yp[i0+2] = fmaf(x4.z, Dv, v2) * s4.z;
      yp[i0+3] = fmaf(x4.w, Dv, v3) * s4.w;
    }
  }
}

// ---------------- out_proj (64->32) into (b,c,l) = NCHW image --------------
__global__ __launch_bounds__(512) void outproj_k(const float* __restrict__ yt,
    const float* __restrict__ Wout, float* __restrict__ ym)
{
  __shared__ float ys[64][68];    // ys[l][d]
  const int tid = threadIdx.x, lane = tid & 63, ty = tid >> 6;
  const int bi = blockIdx.x >> 6;
  const int l0 = (blockIdx.x & 63) << 6;
  for (int r=ty; r<64; r+=8)
    ys[lane][r] = yt[((size_t)(bi*64+r))*SEQL + l0 + lane];
  __syncthreads();
  float yv[64];
  #pragma unroll
  for (int c=0;c<64;c+=4){
    float4 f = *(const float4*)(&ys[lane][c]);
    yv[c]=f.x; yv[c+1]=f.y; yv[c+2]=f.z; yv[c+3]=f.w;
  }
  #pragma unroll
  for (int jj=0;jj<4;++jj){
    int j = ty*4 + jj;
    const float* wr = Wout + j*64;
    float acc = 0.0f;
    #pragma unroll
    for (int c=0;c<64;++c) acc = fmaf(yv[c], wr[c], acc);
    ym[((size_t)(bi*32+j))*SEQL + l0 + lane] = acc;
  }
}

extern "C" void kernel_launch(void* const* d_in, const int* in_sizes, int n_in,
                              void* d_out, int out_size, void* d_ws, size_t ws_size,
                              hipStream_t stream) {
  const float* x        = (const float*)d_in[0];
  const float* conv1_w  = (const float*)d_in[1];
  const float* conv1_b  = (const float*)d_in[2];
  const float* conv2_w  = (const float*)d_in[3];
  const float* conv2_b  = (const float*)d_in[4];
  const float* ln_g     = (const float*)d_in[5];
  const float* ln_b     = (const float*)d_in[6];
  const float* in_proj_w= (const float*)d_in[7];
  const float* conv1d_w = (const float*)d_in[8];
  const float* conv1d_b = (const float*)d_in[9];
  const float* x_proj_w = (const float*)d_in[10];
  const float* dt_proj_w= (const float*)d_in[11];
  const float* dt_proj_b= (const float*)d_in[12];
  const float* A_log    = (const float*)d_in[13];
  const float* Dp       = (const float*)d_in[14];
  const float* out_proj_w=(const float*)d_in[15];
  const float* smooth_w = (const float*)d_in[16];
  const float* smooth_b = (const float*)d_in[17];
  float* out = (float*)d_out;

  float* ws = (float*)d_ws;
  float* t      = ws;                 // (4,64,64,64)  1048576  (free after conv2)
  float* x2     = t      + 1048576;   // (4,32,4096)    524288
  float* xm_pre = x2     + 524288;    // (4,64,4096)   1048576
  float* xm2    = xm_pre + 1048576;   // (4,64,4096)   1048576
  float* szb    = xm2    + 1048576;   // (4,64,4096)   1048576
  float* dlt    = szb    + 1048576;   // (4,64,4096)   1048576
  float* Bmat   = dlt    + 1048576;   // (4,4096,32)    524288
  float* Cmat   = Bmat   + 524288;    // (4,4096,32)    524288
  float* yt     = Cmat   + 524288;    // (4,64,4096)   1048576
  float* ym     = yt     + 1048576;   // (4,32,4096)    524288
  float* cA     = t;                  // (256,64,32)    524288 (aliases t)
  float* cH     = t + 524288;         // (256,64,32)    524288 (aliases t)

  // conv1: 32->64, COG=8 -> grid (64,8,4)=2048 blocks, ksplit=4 (8 ci/wave)
  conv3x3_k<32,64,8,true ,false><<<dim3(64,8,4), 256, 0, stream>>>(x,  conv1_w, conv1_b, nullptr, t);
  // conv2: 64->32 + residual, COG=4 -> grid (64,8,4)=2048 blocks, 16 ci/wave
  conv3x3_k<64,32,4,false,true ><<<dim3(64,8,4), 256, 0, stream>>>(t,  conv2_w, conv2_b, x,       x2);
  ln_inproj_k <<<256, 512, 0, stream>>>(x2, ln_g, ln_b, in_proj_w, xm_pre, szb);
  xproj_k     <<<256, 512, 0, stream>>>(xm_pre, conv1d_w, conv1d_b, x_proj_w, dt_proj_w, dt_proj_b,
                                        xm2, dlt, Bmat, Cmat);
  scan_p1     <<<2048, 256, 0, stream>>>(dlt, xm2, Bmat, A_log, cA, cH);
  scan_comb   <<<64,   128, 0, stream>>>(cA, cH);
  scan_p2     <<<2048, 256, 0, stream>>>(dlt, xm2, Bmat, Cmat, A_log, Dp, szb, cH, yt);
  outproj_k   <<<256, 512, 0, stream>>>(yt, out_proj_w, ym);
  // smooth: 32->32, COG=4 -> grid (64,8,4)=2048 blocks, 8 ci/wave
  conv3x3_k<32,32,4,false,false><<<dim3(64,8,4), 256, 0, stream>>>(ym, smooth_w, smooth_b, nullptr, out);
}

// Round 8
// 242.750 us; speedup vs baseline: 2.0418x; 1.5196x over previous
//
#include <hip/hip_runtime.h>
#include <math.h>

#define SEQL 4096
#define L2E 1.44269504088896340736f

#if defined(__has_builtin)
#if __has_builtin(__builtin_amdgcn_exp2f)
#define FAST_EXP2(x) __builtin_amdgcn_exp2f(x)
#endif
#endif
#ifndef FAST_EXP2
#define FAST_EXP2(x) exp2f(x)
#endif

__device__ __forceinline__ float sigmoid_f(float x){ return 1.0f/(1.0f+expf(-x)); }

// ---------------- conv 3x3, pad 1, 64x64 image, LDS-GEMM style ----------------
// Block 256 thr = 4 waves; wave ty = output row h0+ty, lane = w.
// ci-chunks of 8 staged into padded LDS (float4 global + ds_write_b128, halos
// pre-zeroed -> branch-free compute). Per ci: 9 ds_read_b32 + 9*COG FMA;
// weights via s_load (scalar pipe). COG couts per thread.
template<int CI, int CO, int COG, bool RELU, bool RES>
__global__ __launch_bounds__(256,4) void conv3x3_k(const float* __restrict__ in,
    const float* __restrict__ wgt, const float* __restrict__ bias,
    const float* __restrict__ res, float* __restrict__ out)
{
  constexpr int CIT = 8;
  __shared__ float tin[CIT][6][72];     // [ci][row][col]; data cols 4..67, halos 3 & 68
  const int tid  = threadIdx.x;
  const int lane = tid & 63;            // w
  const int ty   = tid >> 6;            // output row offset 0..3
  const int h0   = blockIdx.x * 4;
  const int co0  = blockIdx.y * COG;
  const int b    = blockIdx.z;

  // zero the column halos once (never overwritten by staging)
  if (tid < CIT*6){
    int cl = tid / 6, r = tid - cl*6;
    tin[cl][r][3]  = 0.0f;
    tin[cl][r][68] = 0.0f;
  }

  float acc[COG];
  #pragma unroll
  for (int u=0;u<COG;++u) acc[u] = 0.0f;

  for (int cig = 0; cig < CI; cig += CIT){
    __syncthreads();
    // stage CIT channels x 6 rows (h0-1 .. h0+4) x 64 cols, float4 granularity
    #pragma unroll
    for (int k=0;k<3;++k){
      int idx4 = tid + k*256;           // 0..767
      int w4   = (idx4 & 15) << 2;
      int rc   = idx4 >> 4;             // 0..47
      int cl   = rc / 6, r = rc - cl*6;
      int h    = h0 - 1 + r;
      float4 v = make_float4(0.0f,0.0f,0.0f,0.0f);
      if (h >= 0 && h < 64)
        v = *(const float4*)(in + ((size_t)(b*CI+cig+cl)*64 + h)*64 + w4);
      *(float4*)&tin[cl][r][4+w4] = v;
    }
    __syncthreads();
    #pragma unroll 4
    for (int ci=0; ci<CIT; ++ci){
      float iv[3][3];
      #pragma unroll
      for (int j=0;j<3;++j)
        #pragma unroll
        for (int c=0;c<3;++c)
          iv[j][c] = tin[ci][ty+j][3+lane+c];   // input[h0+ty-1+j][lane-1+c]
      #pragma unroll
      for (int u=0;u<COG;++u){
        const float* wp = wgt + ((size_t)(co0+u)*CI + cig + ci)*9;  // uniform -> s_load
        #pragma unroll
        for (int j=0;j<3;++j){
          acc[u] = fmaf(iv[j][0], wp[j*3+0], acc[u]);
          acc[u] = fmaf(iv[j][1], wp[j*3+1], acc[u]);
          acc[u] = fmaf(iv[j][2], wp[j*3+2], acc[u]);
        }
      }
    }
  }
  #pragma unroll
  for (int u=0;u<COG;++u){
    size_t ob = ((size_t)(b*CO+co0+u))*4096 + (size_t)(h0+ty)*64 + lane;
    float v = acc[u] + bias[co0+u];
    if constexpr (RES)  v += res[ob];
    if constexpr (RELU) v = fmaxf(v, 0.0f);
    out[ob] = v;
  }
}

// ---------------- LayerNorm(32) + in_proj (32->128) + silu on z half --------
__global__ __launch_bounds__(512) void ln_inproj_k(const float* __restrict__ x2,
    const float* __restrict__ g, const float* __restrict__ be,
    const float* __restrict__ Wip, float* __restrict__ xm_pre, float* __restrict__ sz)
{
  __shared__ float xn[64][36];
  const int tid = threadIdx.x, lane = tid & 63, ty = tid >> 6;
  const int bi = blockIdx.x >> 6;
  const int l0 = (blockIdx.x & 63) << 6;
  if (ty == 0){
    const float* row = x2 + (size_t)bi*131072 + (size_t)(l0+lane)*32;
    float v[32];
    #pragma unroll
    for (int c=0;c<32;c+=4){
      float4 f = *(const float4*)(row + c);
      v[c]=f.x; v[c+1]=f.y; v[c+2]=f.z; v[c+3]=f.w;
    }
    float p[8];
    #pragma unroll
    for (int j2=0;j2<8;++j2) p[j2]=v[j2];
    #pragma unroll
    for (int i=8;i<32;i+=8){
      #pragma unroll
      for (int j2=0;j2<8;++j2) p[j2]+=v[i+j2];
    }
    float mu = (((p[0]+p[1])+(p[2]+p[3]))+((p[4]+p[5])+(p[6]+p[7]))) * 0.03125f;
    float q[8];
    #pragma unroll
    for (int j2=0;j2<8;++j2){ float dd=v[j2]-mu; q[j2]=dd*dd; }
    #pragma unroll
    for (int i=8;i<32;i+=8){
      #pragma unroll
      for (int j2=0;j2<8;++j2){ float dd=v[i+j2]-mu; q[j2]+=dd*dd; }
    }
    float var = (((q[0]+q[1])+(q[2]+q[3]))+((q[4]+q[5])+(q[6]+q[7]))) * 0.03125f;
    float rstd = 1.0f / sqrtf(var + 1e-5f);
    #pragma unroll
    for (int c=0;c<32;++c) xn[lane][c] = (v[c]-mu)*rstd*g[c] + be[c];
  }
  __syncthreads();
  float xv[32];
  #pragma unroll
  for (int c=0;c<32;c+=4){
    float4 f = *(const float4*)(&xn[lane][c]);
    xv[c]=f.x; xv[c+1]=f.y; xv[c+2]=f.z; xv[c+3]=f.w;
  }
  #pragma unroll
  for (int jj=0;jj<16;++jj){
    int j = (ty<<4) + jj;
    const float* wr = Wip + j*32;
    float acc = 0.0f;
    #pragma unroll
    for (int c=0;c<32;++c) acc = fmaf(xv[c], wr[c], acc);
    size_t o = ((size_t)(bi*64 + (j & 63)))*SEQL + l0 + lane;
    if (j < 64) xm_pre[o] = acc;
    else        sz[o] = acc * sigmoid_f(acc);
  }
}

// ---- fused: depthwise causal conv1d+silu, x_proj (64->66), dt_proj+softplus, B/C split
__global__ __launch_bounds__(512) void xproj_k(const float* __restrict__ xm_pre,
    const float* __restrict__ cw, const float* __restrict__ cb,
    const float* __restrict__ Wxp, const float* __restrict__ Wdt,
    const float* __restrict__ bdt, float* __restrict__ xm2,
    float* __restrict__ delta, float* __restrict__ Bm, float* __restrict__ Cm)
{
  __shared__ float xs[64][68];   // xs[d][c] = xm_pre[l0-3+c], c in 0..66
  __shared__ float xt[64][68];   // xt[l][d] = silu(conv) transposed
  __shared__ float xd[64][68];   // xd[l][j], j in 0..65
  const int tid = threadIdx.x, lane = tid & 63, ty = tid >> 6;
  const int bi = blockIdx.x >> 6;
  const int l0 = (blockIdx.x & 63) << 6;
  for (int r=ty; r<64; r+=8){
    const float* src = xm_pre + ((size_t)(bi*64+r))*SEQL + l0;
    float v = 0.0f;
    if (l0 + lane - 3 >= 0) v = src[lane-3];
    xs[r][lane] = v;
    if (lane < 3) xs[r][64+lane] = src[61+lane];
  }
  __syncthreads();
  for (int r=ty; r<64; r+=8){
    float w0=cw[r*4], w1=cw[r*4+1], w2=cw[r*4+2], w3=cw[r*4+3], bv=cb[r];
    float a = xs[r][lane]*w0 + xs[r][lane+1]*w1 + xs[r][lane+2]*w2 + xs[r][lane+3]*w3 + bv;
    float s = a * sigmoid_f(a);
    xt[lane][r] = s;
    xm2[((size_t)(bi*64+r))*SEQL + l0 + lane] = s;
  }
  __syncthreads();
  float xv[64];
  #pragma unroll
  for (int c=0;c<64;c+=4){
    float4 f = *(const float4*)(&xt[lane][c]);
    xv[c]=f.x; xv[c+1]=f.y; xv[c+2]=f.z; xv[c+3]=f.w;
  }
  for (int j=ty; j<66; j+=8){
    const float* wr = Wxp + j*64;
    float acc = 0.0f;
    #pragma unroll
    for (int c=0;c<64;++c) acc = fmaf(xv[c], wr[c], acc);
    xd[lane][j] = acc;
  }
  __syncthreads();
  float dt0 = xd[lane][0], dt1 = xd[lane][1];
  #pragma unroll
  for (int k=0;k<8;++k){
    int d2 = ty*8 + k;
    float v = dt0*Wdt[d2*2] + dt1*Wdt[d2*2+1] + bdt[d2];
    float sp = fmaxf(v,0.0f) + log1pf(expf(-fabsf(v)));
    delta[((size_t)(bi*64+d2))*SEQL + l0 + lane] = sp;
  }
  const int which = ty >> 2, gq = ty & 3;
  float* dst = which ? Cm : Bm;
  size_t base = ((size_t)bi*SEQL + l0 + lane)*32 + gq*8;
  const int s0 = 2 + which*32 + gq*8;
  float4 f0, f1;
  f0.x = xd[lane][s0+0]; f0.y = xd[lane][s0+1]; f0.z = xd[lane][s0+2]; f0.w = xd[lane][s0+3];
  f1.x = xd[lane][s0+4]; f1.y = xd[lane][s0+5]; f1.z = xd[lane][s0+6]; f1.w = xd[lane][s0+7];
  *(float4*)(dst + base)     = f0;
  *(float4*)(dst + base + 4) = f1;
}

// ---------------- selective scan: 3-kernel chunked scan, chunk=64 ----------
__global__ __launch_bounds__(256) void scan_p1(const float* __restrict__ dlt,
    const float* __restrict__ xssm, const float* __restrict__ Bm,
    const float* __restrict__ A_log, float* __restrict__ cA, float* __restrict__ cH)
{
  const int tid = threadIdx.x;
  const int n = tid & 31;
  const int chunk = (blockIdx.x & 7)*8 + (tid >> 5);
  const int bd = blockIdx.x >> 3;
  const int b = bd >> 6, d = bd & 63;
  const int l0 = chunk << 6;
  const float Av2 = -expf(A_log[d*32+n]) * L2E;
  const float* del = dlt  + (size_t)bd*SEQL + l0;
  const float* xp  = xssm + (size_t)bd*SEQL + l0;
  const float* Bp  = Bm + ((size_t)b*SEQL + l0)*32 + n;
  float h = 0.0f, aP = 1.0f;
  #pragma unroll 4
  for (int i0=0;i0<64;i0+=4){
    float4 d4 = *(const float4*)(del+i0);
    float4 x4 = *(const float4*)(xp +i0);
    float b0 = Bp[(i0+0)*32], b1 = Bp[(i0+1)*32], b2 = Bp[(i0+2)*32], b3 = Bp[(i0+3)*32];
    float a0 = FAST_EXP2(d4.x*Av2); h = fmaf(a0,h, d4.x*b0*x4.x); aP *= a0;
    float a1 = FAST_EXP2(d4.y*Av2); h = fmaf(a1,h, d4.y*b1*x4.y); aP *= a1;
    float a2 = FAST_EXP2(d4.z*Av2); h = fmaf(a2,h, d4.z*b2*x4.z); aP *= a2;
    float a3 = FAST_EXP2(d4.w*Av2); h = fmaf(a3,h, d4.w*b3*x4.w); aP *= a3;
  }
  int idx = (bd*64+chunk)*32 + n;
  cA[idx] = aP; cH[idx] = h;
}

__global__ __launch_bounds__(128) void scan_comb(const float* __restrict__ cA,
    float* __restrict__ cH)
{
  const int gid = blockIdx.x*128 + threadIdx.x;   // 8192 = 256 bd x 32 n
  const int n = gid & 31, bd = gid >> 5;
  const size_t base = (size_t)bd*64*32 + n;
  float hrun = 0.0f;
  #pragma unroll 8
  for (int c=0;c<64;++c){
    float ac = cA[base + c*32];
    float hc = cH[base + c*32];
    cH[base + c*32] = hrun;                        // exclusive prefix
    hrun = fmaf(ac, hrun, hc);
  }
}

__global__ __launch_bounds__(256) void scan_p2(const float* __restrict__ dlt,
    const float* __restrict__ xssm, const float* __restrict__ Bm,
    const float* __restrict__ Cm, const float* __restrict__ A_log,
    const float* __restrict__ Dp, const float* __restrict__ sz,
    const float* __restrict__ cH, float* __restrict__ yt)
{
  const int tid = threadIdx.x;
  const int n = tid & 31;
  const int chunk = (blockIdx.x & 7)*8 + (tid >> 5);
  const int bd = blockIdx.x >> 3;
  const int b = bd >> 6, d = bd & 63;
  const int l0 = chunk << 6;
  const float Av2 = -expf(A_log[d*32+n]) * L2E;
  const float Dv = Dp[d];
  const float* del = dlt  + (size_t)bd*SEQL + l0;
  const float* xp  = xssm + (size_t)bd*SEQL + l0;
  const float* szp = sz   + (size_t)bd*SEQL + l0;
  const float* Bp  = Bm + ((size_t)b*SEQL + l0)*32 + n;
  const float* Cp  = Cm + ((size_t)b*SEQL + l0)*32 + n;
  float* yp = yt + (size_t)bd*SEQL + l0;
  float h = cH[(bd*64+chunk)*32 + n];
  #pragma unroll 2
  for (int i0=0;i0<64;i0+=4){
    float4 d4 = *(const float4*)(del+i0);
    float4 x4 = *(const float4*)(xp +i0);
    float4 s4 = *(const float4*)(szp+i0);
    float b0 = Bp[(i0+0)*32], b1 = Bp[(i0+1)*32], b2 = Bp[(i0+2)*32], b3 = Bp[(i0+3)*32];
    float c0 = Cp[(i0+0)*32], c1 = Cp[(i0+1)*32], c2 = Cp[(i0+2)*32], c3 = Cp[(i0+3)*32];
    float a0 = FAST_EXP2(d4.x*Av2); h = fmaf(a0,h, d4.x*b0*x4.x);
    float v0 = h*c0;
    float a1 = FAST_EXP2(d4.y*Av2); h = fmaf(a1,h, d4.y*b1*x4.y);
    float v1 = h*c1;
    float a2 = FAST_EXP2(d4.z*Av2); h = fmaf(a2,h, d4.z*b2*x4.z);
    float v2 = h*c2;
    float a3 = FAST_EXP2(d4.w*Av2); h = fmaf(a3,h, d4.w*b3*x4.w);
    float v3 = h*c3;
    v0 += __shfl_xor(v0,16); v0 += __shfl_xor(v0,8); v0 += __shfl_xor(v0,4);
    v0 += __shfl_xor(v0,2);  v0 += __shfl_xor(v0,1);
    v1 += __shfl_xor(v1,16); v1 += __shfl_xor(v1,8); v1 += __shfl_xor(v1,4);
    v1 += __shfl_xor(v1,2);  v1 += __shfl_xor(v1,1);
    v2 += __shfl_xor(v2,16); v2 += __shfl_xor(v2,8); v2 += __shfl_xor(v2,4);
    v2 += __shfl_xor(v2,2);  v2 += __shfl_xor(v2,1);
    v3 += __shfl_xor(v3,16); v3 += __shfl_xor(v3,8); v3 += __shfl_xor(v3,4);
    v3 += __shfl_xor(v3,2);  v3 += __shfl_xor(v3,1);
    if (n==0){
      yp[i0+0] = fmaf(x4.x, Dv, v0) * s4.x;
      yp[i0+1] = fmaf(x4.y, Dv, v1) * s4.y;
      yp[i0+2] = fmaf(x4.z, Dv, v2) * s4.z;
      yp[i0+3] = fmaf(x4.w, Dv, v3) * s4.w;
    }
  }
}

// ---------------- out_proj (64->32) into (b,c,l) = NCHW image --------------
__global__ __launch_bounds__(512) void outproj_k(const float* __restrict__ yt,
    const float* __restrict__ Wout, float* __restrict__ ym)
{
  __shared__ float ys[64][68];    // ys[l][d]
  const int tid = threadIdx.x, lane = tid & 63, ty = tid >> 6;
  const int bi = blockIdx.x >> 6;
  const int l0 = (blockIdx.x & 63) << 6;
  for (int r=ty; r<64; r+=8)
    ys[lane][r] = yt[((size_t)(bi*64+r))*SEQL + l0 + lane];
  __syncthreads();
  float yv[64];
  #pragma unroll
  for (int c=0;c<64;c+=4){
    float4 f = *(const float4*)(&ys[lane][c]);
    yv[c]=f.x; yv[c+1]=f.y; yv[c+2]=f.z; yv[c+3]=f.w;
  }
  #pragma unroll
  for (int jj=0;jj<4;++jj){
    int j = ty*4 + jj;
    const float* wr = Wout + j*64;
    float acc = 0.0f;
    #pragma unroll
    for (int c=0;c<64;++c) acc = fmaf(yv[c], wr[c], acc);
    ym[((size_t)(bi*32+j))*SEQL + l0 + lane] = acc;
  }
}

extern "C" void kernel_launch(void* const* d_in, const int* in_sizes, int n_in,
                              void* d_out, int out_size, void* d_ws, size_t ws_size,
                              hipStream_t stream) {
  const float* x        = (const float*)d_in[0];
  const float* conv1_w  = (const float*)d_in[1];
  const float* conv1_b  = (const float*)d_in[2];
  const float* conv2_w  = (const float*)d_in[3];
  const float* conv2_b  = (const float*)d_in[4];
  const float* ln_g     = (const float*)d_in[5];
  const float* ln_b     = (const float*)d_in[6];
  const float* in_proj_w= (const float*)d_in[7];
  const float* conv1d_w = (const float*)d_in[8];
  const float* conv1d_b = (const float*)d_in[9];
  const float* x_proj_w = (const float*)d_in[10];
  const float* dt_proj_w= (const float*)d_in[11];
  const float* dt_proj_b= (const float*)d_in[12];
  const float* A_log    = (const float*)d_in[13];
  const float* Dp       = (const float*)d_in[14];
  const float* out_proj_w=(const float*)d_in[15];
  const float* smooth_w = (const float*)d_in[16];
  const float* smooth_b = (const float*)d_in[17];
  float* out = (float*)d_out;

  float* ws = (float*)d_ws;
  float* t      = ws;                 // (4,64,64,64)  1048576  (free after conv2)
  float* x2     = t      + 1048576;   // (4,32,4096)    524288
  float* xm_pre = x2     + 524288;    // (4,64,4096)   1048576
  float* xm2    = xm_pre + 1048576;   // (4,64,4096)   1048576
  float* szb    = xm2    + 1048576;   // (4,64,4096)   1048576
  float* dlt    = szb    + 1048576;   // (4,64,4096)   1048576
  float* Bmat   = dlt    + 1048576;   // (4,4096,32)    524288
  float* Cmat   = Bmat   + 524288;    // (4,4096,32)    524288
  float* yt     = Cmat   + 524288;    // (4,64,4096)   1048576
  float* ym     = yt     + 1048576;   // (4,32,4096)    524288
  float* cA     = t;                  // (256,64,32)    524288 (aliases t)
  float* cH     = t + 524288;         // (256,64,32)    524288 (aliases t)

  // conv1: 32->64, COG=4 -> grid (16,16,4)=1024 blocks
  conv3x3_k<32,64,4,true ,false><<<dim3(16,16,4), 256, 0, stream>>>(x,  conv1_w, conv1_b, nullptr, t);
  // conv2: 64->32 + residual, COG=4 -> grid (16,8,4)=512 blocks
  conv3x3_k<64,32,4,false,true ><<<dim3(16,8,4), 256, 0, stream>>>(t,  conv2_w, conv2_b, x,       x2);
  ln_inproj_k <<<256, 512, 0, stream>>>(x2, ln_g, ln_b, in_proj_w, xm_pre, szb);
  xproj_k     <<<256, 512, 0, stream>>>(xm_pre, conv1d_w, conv1d_b, x_proj_w, dt_proj_w, dt_proj_b,
                                        xm2, dlt, Bmat, Cmat);
  scan_p1     <<<2048, 256, 0, stream>>>(dlt, xm2, Bmat, A_log, cA, cH);
  scan_comb   <<<64,   128, 0, stream>>>(cA, cH);
  scan_p2     <<<2048, 256, 0, stream>>>(dlt, xm2, Bmat, Cmat, A_log, Dp, szb, cH, yt);
  outproj_k   <<<256, 512, 0, stream>>>(yt, out_proj_w, ym);
  // smooth: 32->32, COG=4 -> grid (16,8,4)=512 blocks
  conv3x3_k<32,32,4,false,false><<<dim3(16,8,4), 256, 0, stream>>>(ym, smooth_w, smooth_b, nullptr, out);
}

// Round 9
// 223.610 us; speedup vs baseline: 2.2165x; 1.0856x over previous
//
#include <hip/hip_runtime.h>
#include <math.h>

#define SEQL 4096
#define L2E 1.44269504088896340736f

#if defined(__has_builtin)
#if __has_builtin(__builtin_amdgcn_exp2f)
#define FAST_EXP2(x) __builtin_amdgcn_exp2f(x)
#endif
#endif
#ifndef FAST_EXP2
#define FAST_EXP2(x) exp2f(x)
#endif

__device__ __forceinline__ float sigmoid_f(float x){ return 1.0f/(1.0f+expf(-x)); }

// ---------------- conv 3x3, pad 1, 64x64 image ----------------
// Block 256 = 4 waves. Wave ty owns ci-slice [ty*CIT,(ty+1)*CIT) with a
// PRIVATE LDS staging region -> no barriers in the main loop (intra-wave
// lgkm ordering only). Per 2-ci chunk: 3 float4 global + 3 ds_write_b128 per
// lane, then per ci 18 ds_read_b32 + COG*4*9 FMA (8 FMA/ds at COG=4).
// One final cross-wave reduction barrier. 4 output rows x COG couts.
template<int CI, int CO, int COG, bool RELU, bool RES>
__global__ __launch_bounds__(256) void conv3x3_k(const float* __restrict__ in,
    const float* __restrict__ wgt, const float* __restrict__ bias,
    const float* __restrict__ res, float* __restrict__ out)
{
  constexpr int CIT = CI/4;
  __shared__ float tin[4][2][6][72];    // [wave][ci_local][row][col]; data 4..67, halos 3,68
  __shared__ float red[3][4][COG][66];  // partials from waves 1..3
  const int tid  = threadIdx.x;
  const int lane = tid & 63;            // w
  const int ty   = tid >> 6;            // wave id = ci-slice
  const int h0   = blockIdx.x * 4;
  const int co0  = blockIdx.y * COG;
  const int b    = blockIdx.z;

  // zero my wave's column halos once (never touched by staging)
  if (lane < 24){
    int cl = lane / 12, rem = lane % 12, r = rem >> 1, side = rem & 1;
    tin[ty][cl][r][side ? 68 : 3] = 0.0f;
  }

  float acc[4][COG];
  #pragma unroll
  for (int rr=0;rr<4;++rr)
    #pragma unroll
    for (int u=0;u<COG;++u) acc[rr][u] = 0.0f;

  const int ci0 = ty*CIT;
  for (int cig = ci0; cig < ci0 + CIT; cig += 2){
    // stage 2 channels x 6 rows (h0-1..h0+4) x 64 cols, float4
    #pragma unroll
    for (int k=0;k<3;++k){
      int idx4 = lane + k*64;           // 0..191
      int row  = idx4 >> 4;             // 0..11
      int cl   = row / 6, r = row - cl*6;
      int w4   = (idx4 & 15) << 2;
      int h    = h0 - 1 + r;
      float4 v = make_float4(0.0f,0.0f,0.0f,0.0f);
      if (h >= 0 && h < 64)
        v = *(const float4*)(in + ((size_t)(b*CI+cig+cl)*64 + h)*64 + w4);
      *(float4*)&tin[ty][cl][r][4+w4] = v;
    }
    #pragma unroll
    for (int cl=0; cl<2; ++cl){
      float rv[6][3];
      #pragma unroll
      for (int r=0;r<6;++r)
        #pragma unroll
        for (int c=0;c<3;++c)
          rv[r][c] = tin[ty][cl][r][3+lane+c];
      #pragma unroll
      for (int u=0;u<COG;++u){
        const float* wp = wgt + ((size_t)(co0+u)*CI + cig + cl)*9;  // uniform -> s_load
        #pragma unroll
        for (int rr=0;rr<4;++rr)
          #pragma unroll
          for (int j=0;j<3;++j){
            acc[rr][u] = fmaf(rv[rr+j][0], wp[j*3+0], acc[rr][u]);
            acc[rr][u] = fmaf(rv[rr+j][1], wp[j*3+1], acc[rr][u]);
            acc[rr][u] = fmaf(rv[rr+j][2], wp[j*3+2], acc[rr][u]);
          }
      }
    }
  }
  if (ty > 0){
    #pragma unroll
    for (int rr=0;rr<4;++rr)
      #pragma unroll
      for (int u=0;u<COG;++u) red[ty-1][rr][u][lane] = acc[rr][u];
  }
  __syncthreads();
  if (ty == 0){
    #pragma unroll
    for (int rr=0;rr<4;++rr)
      #pragma unroll
      for (int u=0;u<COG;++u){
        float s = acc[rr][u] + red[0][rr][u][lane] + red[1][rr][u][lane]
                + red[2][rr][u][lane] + bias[co0+u];
        size_t ob = ((size_t)(b*CO+co0+u)*64 + h0+rr)*64 + lane;
        if constexpr (RES)  s += res[ob];
        if constexpr (RELU) s = fmaxf(s, 0.0f);
        out[ob] = s;
      }
  }
}

// ---- fused: LN(32) + in_proj(32->128) + silu(z) + depthwise conv1d(k=4)+silu
//      + x_proj(64->66) + dt_proj+softplus + B/C split. One block per l-tile.
//      Halo tokens l0-3..l0-1 recomputed exactly (LN/in_proj are per-token).
__global__ __launch_bounds__(512) void mamba_in_k(const float* __restrict__ x2,
    const float* __restrict__ g, const float* __restrict__ be,
    const float* __restrict__ Wip, const float* __restrict__ cw,
    const float* __restrict__ cb, const float* __restrict__ Wxp,
    const float* __restrict__ Wdt, const float* __restrict__ bdt,
    float* __restrict__ xm2, float* __restrict__ szb, float* __restrict__ dlt,
    float* __restrict__ Bm, float* __restrict__ Cm)
{
  __shared__ float xn[68][36];   // LN'd tokens, idx t=0..66 <-> token l0-3+t
  __shared__ float xm[64][68];   // in_proj xm half [d][t]
  __shared__ float xt[64][68];   // silu(conv) transposed [l-local][d]
  __shared__ float xd[64][68];   // x_dbl [l-local][j]
  const int tid = threadIdx.x, lane = tid & 63, ty = tid >> 6;  // ty 0..7
  const int bi = blockIdx.x >> 6;
  const int l0 = (blockIdx.x & 63) << 6;

  if (ty < 2){
    int t = ty*64 + lane;
    if (t < 67){
      int tok = l0 - 3 + t;
      if (tok >= 0){
        const float* row = x2 + (size_t)bi*131072 + (size_t)tok*32;
        float v[32];
        #pragma unroll
        for (int c=0;c<32;c+=4){
          float4 f = *(const float4*)(row + c);
          v[c]=f.x; v[c+1]=f.y; v[c+2]=f.z; v[c+3]=f.w;
        }
        float p[8];
        #pragma unroll
        for (int j2=0;j2<8;++j2) p[j2]=v[j2];
        #pragma unroll
        for (int i=8;i<32;i+=8){
          #pragma unroll
          for (int j2=0;j2<8;++j2) p[j2]+=v[i+j2];
        }
        float mu = (((p[0]+p[1])+(p[2]+p[3]))+((p[4]+p[5])+(p[6]+p[7]))) * 0.03125f;
        float q[8];
        #pragma unroll
        for (int j2=0;j2<8;++j2){ float dd=v[j2]-mu; q[j2]=dd*dd; }
        #pragma unroll
        for (int i=8;i<32;i+=8){
          #pragma unroll
          for (int j2=0;j2<8;++j2){ float dd=v[i+j2]-mu; q[j2]+=dd*dd; }
        }
        float var = (((q[0]+q[1])+(q[2]+q[3]))+((q[4]+q[5])+(q[6]+q[7]))) * 0.03125f;
        float rstd = 1.0f / sqrtf(var + 1e-5f);
        #pragma unroll
        for (int c=0;c<32;++c) xn[t][c] = (v[c]-mu)*rstd*g[c] + be[c];
      } else {
        #pragma unroll
        for (int c=0;c<32;++c) xn[t][c] = 0.0f;
      }
    }
  }
  __syncthreads();

  const int d0 = ty*8;
  {
    float xvA[32];
    #pragma unroll
    for (int c=0;c<32;c+=4){
      float4 f = *(const float4*)(&xn[lane][c]);
      xvA[c]=f.x; xvA[c+1]=f.y; xvA[c+2]=f.z; xvA[c+3]=f.w;
    }
    #pragma unroll
    for (int jj=0;jj<8;++jj){
      const float* wr = Wip + (d0+jj)*32;
      float a = 0.0f;
      #pragma unroll
      for (int c=0;c<32;++c) a = fmaf(xvA[c], wr[c], a);
      xm[d0+jj][lane] = a;
    }
  }
  if (lane < 3){
    float xvB[32];
    #pragma unroll
    for (int c=0;c<32;c+=4){
      float4 f = *(const float4*)(&xn[64+lane][c]);
      xvB[c]=f.x; xvB[c+1]=f.y; xvB[c+2]=f.z; xvB[c+3]=f.w;
    }
    #pragma unroll
    for (int jj=0;jj<8;++jj){
      const float* wr = Wip + (d0+jj)*32;
      float a = 0.0f;
      #pragma unroll
      for (int c=0;c<32;++c) a = fmaf(xvB[c], wr[c], a);
      xm[d0+jj][64+lane] = a;
    }
  }
  {
    float xvC[32];
    #pragma unroll
    for (int c=0;c<32;c+=4){
      float4 f = *(const float4*)(&xn[lane+3][c]);
      xvC[c]=f.x; xvC[c+1]=f.y; xvC[c+2]=f.z; xvC[c+3]=f.w;
    }
    #pragma unroll
    for (int jj=0;jj<8;++jj){
      const float* wr = Wip + (64+d0+jj)*32;
      float a = 0.0f;
      #pragma unroll
      for (int c=0;c<32;++c) a = fmaf(xvC[c], wr[c], a);
      szb[((size_t)(bi*64+d0+jj))*SEQL + l0 + lane] = a * sigmoid_f(a);
    }
  }
  __syncthreads();

  #pragma unroll
  for (int jj=0;jj<8;++jj){
    int d = d0 + jj;
    float a = xm[d][lane]*cw[d*4] + xm[d][lane+1]*cw[d*4+1]
            + xm[d][lane+2]*cw[d*4+2] + xm[d][lane+3]*cw[d*4+3] + cb[d];
    float s = a * sigmoid_f(a);
    xt[lane][d] = s;
    xm2[((size_t)(bi*64+d))*SEQL + l0 + lane] = s;
  }
  __syncthreads();

  float xv[64];
  #pragma unroll
  for (int c=0;c<64;c+=4){
    float4 f = *(const float4*)(&xt[lane][c]);
    xv[c]=f.x; xv[c+1]=f.y; xv[c+2]=f.z; xv[c+3]=f.w;
  }
  for (int j=ty; j<66; j+=8){
    const float* wr = Wxp + j*64;
    float a = 0.0f;
    #pragma unroll
    for (int c=0;c<64;++c) a = fmaf(xv[c], wr[c], a);
    xd[lane][j] = a;
  }
  __syncthreads();

  float dt0 = xd[lane][0], dt1 = xd[lane][1];
  #pragma unroll
  for (int k=0;k<8;++k){
    int d2 = ty*8 + k;
    float v = dt0*Wdt[d2*2] + dt1*Wdt[d2*2+1] + bdt[d2];
    float sp = fmaxf(v,0.0f) + log1pf(expf(-fabsf(v)));
    dlt[((size_t)(bi*64+d2))*SEQL + l0 + lane] = sp;
  }
  const int which = ty >> 2, gq = ty & 3;
  float* dst = which ? Cm : Bm;
  size_t base = ((size_t)bi*SEQL + l0 + lane)*32 + gq*8;
  const int s0 = 2 + which*32 + gq*8;
  float4 f0, f1;
  f0.x = xd[lane][s0+0]; f0.y = xd[lane][s0+1]; f0.z = xd[lane][s0+2]; f0.w = xd[lane][s0+3];
  f1.x = xd[lane][s0+4]; f1.y = xd[lane][s0+5]; f1.z = xd[lane][s0+6]; f1.w = xd[lane][s0+7];
  *(float4*)(dst + base)     = f0;
  *(float4*)(dst + base + 4) = f1;
}

// ---------------- selective scan: 3-kernel chunked scan, chunk=64 ----------
__global__ __launch_bounds__(256) void scan_p1(const float* __restrict__ dlt,
    const float* __restrict__ xssm, const float* __restrict__ Bm,
    const float* __restrict__ A_log, float* __restrict__ cA, float* __restrict__ cH)
{
  const int tid = threadIdx.x;
  const int n = tid & 31;
  const int chunk = (blockIdx.x & 7)*8 + (tid >> 5);
  const int bd = blockIdx.x >> 3;
  const int b = bd >> 6, d = bd & 63;
  const int l0 = chunk << 6;
  const float Av2 = -expf(A_log[d*32+n]) * L2E;
  const float* del = dlt  + (size_t)bd*SEQL + l0;
  const float* xp  = xssm + (size_t)bd*SEQL + l0;
  const float* Bp  = Bm + ((size_t)b*SEQL + l0)*32 + n;
  float h = 0.0f, aP = 1.0f;
  #pragma unroll 4
  for (int i0=0;i0<64;i0+=4){
    float4 d4 = *(const float4*)(del+i0);
    float4 x4 = *(const float4*)(xp +i0);
    float b0 = Bp[(i0+0)*32], b1 = Bp[(i0+1)*32], b2 = Bp[(i0+2)*32], b3 = Bp[(i0+3)*32];
    float a0 = FAST_EXP2(d4.x*Av2); h = fmaf(a0,h, d4.x*b0*x4.x); aP *= a0;
    float a1 = FAST_EXP2(d4.y*Av2); h = fmaf(a1,h, d4.y*b1*x4.y); aP *= a1;
    float a2 = FAST_EXP2(d4.z*Av2); h = fmaf(a2,h, d4.z*b2*x4.z); aP *= a2;
    float a3 = FAST_EXP2(d4.w*Av2); h = fmaf(a3,h, d4.w*b3*x4.w); aP *= a3;
  }
  int idx = (bd*64+chunk)*32 + n;
  cA[idx] = aP; cH[idx] = h;
}

__global__ __launch_bounds__(128) void scan_comb(const float* __restrict__ cA,
    float* __restrict__ cH)
{
  const int gid = blockIdx.x*128 + threadIdx.x;   // 8192 = 256 bd x 32 n
  const int n = gid & 31, bd = gid >> 5;
  const size_t base = (size_t)bd*64*32 + n;
  float hrun = 0.0f;
  #pragma unroll 8
  for (int c=0;c<64;++c){
    float ac = cA[base + c*32];
    float hc = cH[base + c*32];
    cH[base + c*32] = hrun;                        // exclusive prefix
    hrun = fmaf(ac, hrun, hc);
  }
}

__global__ __launch_bounds__(256) void scan_p2(const float* __restrict__ dlt,
    const float* __restrict__ xssm, const float* __restrict__ Bm,
    const float* __restrict__ Cm, const float* __restrict__ A_log,
    const float* __restrict__ Dp, const float* __restrict__ sz,
    const float* __restrict__ cH, float* __restrict__ yt)
{
  const int tid = threadIdx.x;
  const int n = tid & 31;
  const int chunk = (blockIdx.x & 7)*8 + (tid >> 5);
  const int bd = blockIdx.x >> 3;
  const int b = bd >> 6, d = bd & 63;
  const int l0 = chunk << 6;
  const float Av2 = -expf(A_log[d*32+n]) * L2E;
  const float Dv = Dp[d];
  const float* del = dlt  + (size_t)bd*SEQL + l0;
  const float* xp  = xssm + (size_t)bd*SEQL + l0;
  const float* szp = sz   + (size_t)bd*SEQL + l0;
  const float* Bp  = Bm + ((size_t)b*SEQL + l0)*32 + n;
  const float* Cp  = Cm + ((size_t)b*SEQL + l0)*32 + n;
  float* yp = yt + (size_t)bd*SEQL + l0;
  float h = cH[(bd*64+chunk)*32 + n];
  #pragma unroll 2
  for (int i0=0;i0<64;i0+=4){
    float4 d4 = *(const float4*)(del+i0);
    float4 x4 = *(const float4*)(xp +i0);
    float4 s4 = *(const float4*)(szp+i0);
    float b0 = Bp[(i0+0)*32], b1 = Bp[(i0+1)*32], b2 = Bp[(i0+2)*32], b3 = Bp[(i0+3)*32];
    float c0 = Cp[(i0+0)*32], c1 = Cp[(i0+1)*32], c2 = Cp[(i0+2)*32], c3 = Cp[(i0+3)*32];
    float a0 = FAST_EXP2(d4.x*Av2); h = fmaf(a0,h, d4.x*b0*x4.x);
    float v0 = h*c0;
    float a1 = FAST_EXP2(d4.y*Av2); h = fmaf(a1,h, d4.y*b1*x4.y);
    float v1 = h*c1;
    float a2 = FAST_EXP2(d4.z*Av2); h = fmaf(a2,h, d4.z*b2*x4.z);
    float v2 = h*c2;
    float a3 = FAST_EXP2(d4.w*Av2); h = fmaf(a3,h, d4.w*b3*x4.w);
    float v3 = h*c3;
    v0 += __shfl_xor(v0,16); v0 += __shfl_xor(v0,8); v0 += __shfl_xor(v0,4);
    v0 += __shfl_xor(v0,2);  v0 += __shfl_xor(v0,1);
    v1 += __shfl_xor(v1,16); v1 += __shfl_xor(v1,8); v1 += __shfl_xor(v1,4);
    v1 += __shfl_xor(v1,2);  v1 += __shfl_xor(v1,1);
    v2 += __shfl_xor(v2,16); v2 += __shfl_xor(v2,8); v2 += __shfl_xor(v2,4);
    v2 += __shfl_xor(v2,2);  v2 += __shfl_xor(v2,1);
    v3 += __shfl_xor(v3,16); v3 += __shfl_xor(v3,8); v3 += __shfl_xor(v3,4);
    v3 += __shfl_xor(v3,2);  v3 += __shfl_xor(v3,1);
    if (n==0){
      yp[i0+0] = fmaf(x4.x, Dv, v0) * s4.x;
      yp[i0+1] = fmaf(x4.y, Dv, v1) * s4.y;
      yp[i0+2] = fmaf(x4.z, Dv, v2) * s4.z;
      yp[i0+3] = fmaf(x4.w, Dv, v3) * s4.w;
    }
  }
}

// ---------------- out_proj (64->32) into (b,c,l) = NCHW image --------------
__global__ __launch_bounds__(512) void outproj_k(const float* __restrict__ yt,
    const float* __restrict__ Wout, float* __restrict__ ym)
{
  __shared__ float ys[64][68];    // ys[l][d]
  const int tid = threadIdx.x, lane = tid & 63, ty = tid >> 6;
  const int bi = blockIdx.x >> 6;
  const int l0 = (blockIdx.x & 63) << 6;
  for (int r=ty; r<64; r+=8)
    ys[lane][r] = yt[((size_t)(bi*64+r))*SEQL + l0 + lane];
  __syncthreads();
  float yv[64];
  #pragma unroll
  for (int c=0;c<64;c+=4){
    float4 f = *(const float4*)(&ys[lane][c]);
    yv[c]=f.x; yv[c+1]=f.y; yv[c+2]=f.z; yv[c+3]=f.w;
  }
  #pragma unroll
  for (int jj=0;jj<4;++jj){
    int j = ty*4 + jj;
    const float* wr = Wout + j*64;
    float acc = 0.0f;
    #pragma unroll
    for (int c=0;c<64;++c) acc = fmaf(yv[c], wr[c], acc);
    ym[((size_t)(bi*32+j))*SEQL + l0 + lane] = acc;
  }
}

extern "C" void kernel_launch(void* const* d_in, const int* in_sizes, int n_in,
                              void* d_out, int out_size, void* d_ws, size_t ws_size,
                              hipStream_t stream) {
  const float* x        = (const float*)d_in[0];
  const float* conv1_w  = (const float*)d_in[1];
  const float* conv1_b  = (const float*)d_in[2];
  const float* conv2_w  = (const float*)d_in[3];
  const float* conv2_b  = (const float*)d_in[4];
  const float* ln_g     = (const float*)d_in[5];
  const float* ln_b     = (const float*)d_in[6];
  const float* in_proj_w= (const float*)d_in[7];
  const float* conv1d_w = (const float*)d_in[8];
  const float* conv1d_b = (const float*)d_in[9];
  const float* x_proj_w = (const float*)d_in[10];
  const float* dt_proj_w= (const float*)d_in[11];
  const float* dt_proj_b= (const float*)d_in[12];
  const float* A_log    = (const float*)d_in[13];
  const float* Dp       = (const float*)d_in[14];
  const float* out_proj_w=(const float*)d_in[15];
  const float* smooth_w = (const float*)d_in[16];
  const float* smooth_b = (const float*)d_in[17];
  float* out = (float*)d_out;

  float* ws = (float*)d_ws;
  float* t      = ws;                 // (4,64,64,64)  1048576  (free after conv2)
  float* x2     = t      + 1048576;   // (4,32,4096)    524288
  float* xm2    = x2     + 524288;    // (4,64,4096)   1048576
  float* szb    = xm2    + 1048576;   // (4,64,4096)   1048576
  float* dlt    = szb    + 1048576;   // (4,64,4096)   1048576
  float* Bmat   = dlt    + 1048576;   // (4,4096,32)    524288
  float* Cmat   = Bmat   + 524288;    // (4,4096,32)    524288
  float* yt     = Cmat   + 524288;    // (4,64,4096)   1048576
  float* ym     = yt     + 1048576;   // (4,32,4096)    524288
  float* cA     = t;                  // (256,64,32)    524288 (aliases t)
  float* cH     = t + 524288;         // (256,64,32)    524288 (aliases t)

  // conv1: 32->64, COG=4 -> grid (16,16,4)=1024 blocks, wave-private ci-slices
  conv3x3_k<32,64,4,true ,false><<<dim3(16,16,4), 256, 0, stream>>>(x,  conv1_w, conv1_b, nullptr, t);
  // conv2: 64->32 + residual -> grid (16,8,4)=512 blocks
  conv3x3_k<64,32,4,false,true ><<<dim3(16,8,4), 256, 0, stream>>>(t,  conv2_w, conv2_b, x,       x2);
  mamba_in_k  <<<256, 512, 0, stream>>>(x2, ln_g, ln_b, in_proj_w, conv1d_w, conv1d_b,
                                        x_proj_w, dt_proj_w, dt_proj_b,
                                        xm2, szb, dlt, Bmat, Cmat);
  scan_p1     <<<2048, 256, 0, stream>>>(dlt, xm2, Bmat, A_log, cA, cH);
  scan_comb   <<<64,   128, 0, stream>>>(cA, cH);
  scan_p2     <<<2048, 256, 0, stream>>>(dlt, xm2, Bmat, Cmat, A_log, Dp, szb, cH, yt);
  outproj_k   <<<256, 512, 0, stream>>>(yt, out_proj_w, ym);
  // smooth: 32->32 -> grid (16,8,4)=512 blocks
  conv3x3_k<32,32,4,false,false><<<dim3(16,8,4), 256, 0, stream>>>(ym, smooth_w, smooth_b, nullptr, out);
}